// Round 1
// baseline (32421.933 us; speedup 1.0000x reference)
//
#include <hip/hip_runtime.h>
#include <hip/hip_bf16.h>
#include <hip/hip_fp16.h>
#include <stdint.h>

// MambaBlock: B=64 T=2048 IN=256 STATE=512 OUT=256 K=3
// Pipeline: prep -> x->bf16 -> G1(silu proj) -> G2(conv-as-GEMM) -> BN stats
//           -> fold BN into Bm -> G3(U = conv_raw@Bm'+bias) -> scan -> G4(Y=S@C)

using bf16 = __hip_bfloat16;
typedef short  bf16x8 __attribute__((ext_vector_type(8)));
typedef float  f32x4v __attribute__((ext_vector_type(4)));
typedef _Float16 f16x2 __attribute__((ext_vector_type(2)));

static __device__ inline unsigned short f2bf_bits(float f) {
  union { bf16 h; unsigned short u; } cv; cv.h = __float2bfloat16(f); return cv.u;
}

static __device__ inline float fdot2a(f16x2 a, f16x2 b, float c) {
#if __has_builtin(__builtin_amdgcn_fdot2)
  return __builtin_amdgcn_fdot2(a, b, c, false);
#else
  return c + (float)a[0]*(float)b[0] + (float)a[1]*(float)b[1];
#endif
}

// async global->LDS, 16B per lane; LDS dest = wave-uniform base + lane*16
static __device__ inline void glds16(const bf16* g, short* l) {
  __builtin_amdgcn_global_load_lds(
      (const __attribute__((address_space(1))) unsigned int*)g,
      (__attribute__((address_space(3))) unsigned int*)l, 16, 0, 0);
}

// ---------------- prep: zero sums + vpad edges, build bf16/f16 weights ----------------
__global__ void kprep(const float* __restrict__ W_in, const float* __restrict__ conv_w,
                      const float* __restrict__ A, const float* __restrict__ C,
                      float* __restrict__ sums, bf16* __restrict__ vpad,
                      bf16* __restrict__ Wt, bf16* __restrict__ Wct,
                      f16x2* __restrict__ Apk, bf16* __restrict__ Ct) {
  long idx = (long)blockIdx.x * 256 + threadIdx.x;
  if (idx < 1024) { sums[idx] = 0.f; return; }
  idx -= 1024;
  if (idx < 65536) {  // zero pad rows (t=-1, t=T) of vpad (64 x 2050 x 512)
    long b = idx >> 10, rem = idx & 1023, r = rem >> 9, col = rem & 511;
    long row = b * 2050 + (r ? 2049 : 0);
    vpad[row * 512 + col] = __float2bfloat16(0.f);
    return;
  }
  idx -= 65536;
  if (idx < 131072) { Wt[idx] = __float2bfloat16(W_in[idx]); return; } // W_in already (N=512,K=256)
  idx -= 131072;
  if (idx < 786432) { // Wct[o][kk*512+i] = conv_w[o,i,kk]   (N=512, K=1536)
    long o = idx / 1536, k = idx - o * 1536, kk = k >> 9, i = k & 511;
    Wct[idx] = __float2bfloat16(conv_w[(o * 512 + i) * 3 + kk]);
    return;
  }
  idx -= 786432;
  if (idx < 131072) { // Apk[o][i2] = (A[2*i2][o], A[2*i2+1][o])  f16, o-major for b128 loads
    long o = idx >> 8, i2 = idx & 255;
    f16x2 p; p[0] = (_Float16)A[(2 * i2) * 512 + o]; p[1] = (_Float16)A[(2 * i2 + 1) * 512 + o];
    Apk[idx] = p;
    return;
  }
  idx -= 131072;
  if (idx < 131072) { // Ct[n][i] = C[i][n]   (N=256, K=512)
    long n = idx >> 9, i = idx & 511;
    Ct[idx] = __float2bfloat16(C[i * 256 + n]);
  }
}

// ---------------- x fp32 -> bf16, x4 vectorized ----------------
__global__ void kx(const float4* __restrict__ x, ushort4* __restrict__ xb) {
  size_t i = (size_t)blockIdx.x * 256 + threadIdx.x;
  float4 v = x[i];
  ushort4 o;
  o.x = f2bf_bits(v.x); o.y = f2bf_bits(v.y); o.z = f2bf_bits(v.z); o.w = f2bf_bits(v.w);
  xb[i] = o;
}

// ---------------- 128x128 MFMA GEMM, BK=64, 4 waves, epilogue variants ----------------
// EPI 0: +bias, silu, bf16 -> vpad scatter    EPI 1: bf16 store (stride 512)
// EPI 2: +bias, bf16 store (stride 512)       EPI 3: fp32 store (stride 256)
template <int EPI>
__global__ __launch_bounds__(256)
void kgemm(const bf16* __restrict__ Ag, long lda, long rowExtra,
           const bf16* __restrict__ Bg, int K,
           const float* __restrict__ bias, void* __restrict__ outp) {
  const int tid = threadIdx.x;
  const int lane = tid & 63;
  const int wv = tid >> 6;
  const int wm = wv >> 1, wn = wv & 1;
  const long m0 = (long)blockIdx.x * 128;
  const long n0 = (long)blockIdx.y * 128;
  __shared__ short At[128 * 64];
  __shared__ short Bt[128 * 64];
  f32x4v acc[4][4];
#pragma unroll
  for (int a = 0; a < 4; ++a)
#pragma unroll
    for (int b = 0; b < 4; ++b)
#pragma unroll
      for (int r = 0; r < 4; ++r) acc[a][b][r] = 0.f;

  const int rsub = lane >> 3;       // row within 8-row chunk
  const int ksub = (lane & 7) * 8;  // element offset within 64-wide k slab

  for (int k0 = 0; k0 < K; k0 += 64) {
#pragma unroll
    for (int j = 0; j < 4; ++j) {
      const int c = wv * 4 + j;  // chunk 0..15, 1KB each
      {
        long row = m0 + c * 8 + rsub;
        const bf16* gp = Ag + row * lda + (row >> 11) * rowExtra + k0 + ksub;
        glds16(gp, At + c * 512);
      }
      {
        long row = n0 + c * 8 + rsub;
        const bf16* gp = Bg + row * (long)K + k0 + ksub;
        glds16(gp, Bt + c * 512);
      }
    }
    __syncthreads();
#pragma unroll
    for (int h = 0; h < 2; ++h) {
      bf16x8 af[4], bf_[4];
      const int kb = h * 32 + (lane >> 4) * 8;
#pragma unroll
      for (int f = 0; f < 4; ++f) {
        af[f]  = *(const bf16x8*)(At + (wm * 64 + f * 16 + (lane & 15)) * 64 + kb);
        bf_[f] = *(const bf16x8*)(Bt + (wn * 64 + f * 16 + (lane & 15)) * 64 + kb);
      }
#pragma unroll
      for (int fm = 0; fm < 4; ++fm)
#pragma unroll
        for (int fn = 0; fn < 4; ++fn)
          acc[fm][fn] = __builtin_amdgcn_mfma_f32_16x16x32_bf16(af[fm], bf_[fn], acc[fm][fn], 0, 0, 0);
    }
    __syncthreads();
  }

  const int q = lane >> 4, cL = lane & 15;
#pragma unroll
  for (int fm = 0; fm < 4; ++fm)
#pragma unroll
    for (int fn = 0; fn < 4; ++fn)
#pragma unroll
      for (int r = 0; r < 4; ++r) {
        const long m = m0 + wm * 64 + fm * 16 + q * 4 + r;
        const long n = n0 + wn * 64 + fn * 16 + cL;
        float v = acc[fm][fn][r];
        if constexpr (EPI == 0) {
          v += bias[n];
          const float s = v / (1.f + __expf(-v));
          const long row = (m >> 11) * 2050 + (m & 2047) + 1;
          ((bf16*)outp)[row * 512 + n] = __float2bfloat16(s);
        } else if constexpr (EPI == 1) {
          ((bf16*)outp)[m * 512 + n] = __float2bfloat16(v);
        } else if constexpr (EPI == 2) {
          ((bf16*)outp)[m * 512 + n] = __float2bfloat16(v + bias[n]);
        } else {
          ((float*)outp)[m * 256 + n] = v;
        }
      }
}

// ---------------- BN stats: per-channel sum / sumsq over 131072 rows ----------------
__global__ __launch_bounds__(512)
void bn_stats(const bf16* __restrict__ cr, float* __restrict__ sums) {
  const int tid = threadIdx.x;  // channel
  const long base = (long)blockIdx.x * 128 * 512;
  float s = 0.f, q = 0.f;
  for (int r = 0; r < 128; ++r) {
    float v = __bfloat162float(cr[base + (long)r * 512 + tid]);
    s += v; q += v * v;
  }
  atomicAdd(&sums[tid], s);
  atomicAdd(&sums[512 + tid], q);
}

__global__ void bn_finalize(const float* __restrict__ sums, const float* __restrict__ gamma,
                            const float* __restrict__ beta, float* __restrict__ scsh) {
  const int n = threadIdx.x;
  const float mu = sums[n] * (1.f / 131072.f);
  const float var = sums[512 + n] * (1.f / 131072.f) - mu * mu;
  const float sc = gamma[n] * rsqrtf(var + 1e-5f);
  scsh[n] = sc;
  scsh[512 + n] = beta[n] - mu * sc;   // conv bias cancels in training-mode BN
}

// Bmt[n][i] = Bm[i][n]*sc[i] ; bias_u[n] = sum_i sh[i]*Bm[i][n]
__global__ void build_bm(const float* __restrict__ Bm, const float* __restrict__ scsh,
                         bf16* __restrict__ Bmt, float* __restrict__ biasu) {
  long idx = (long)blockIdx.x * 256 + threadIdx.x;
  if (idx < 262144) {
    long n = idx >> 9, i = idx & 511;
    Bmt[idx] = __float2bfloat16(Bm[i * 512 + n] * scsh[i]);
  } else if (idx < 262656) {
    int n = (int)(idx - 262144);
    float acc = 0.f;
    for (int i = 0; i < 512; ++i) acc += scsh[512 + i] * Bm[(long)i * 512 + n];
    biasu[n] = acc;
  }
}

// ---------------- sequential scan: s = LN(s@A + u_t), 2 batches per WG ----------------
__global__ __launch_bounds__(512)
void krec(const uint4* __restrict__ Apk, const bf16* __restrict__ U,
          const float* __restrict__ lng, const float* __restrict__ lnb,
          bf16* __restrict__ S) {
  const int tid = threadIdx.x;          // output channel o
  const int lane = tid & 63, wv = tid >> 6;
  const long b0 = (long)blockIdx.x * 2, b1 = b0 + 1;
  __shared__ _Float16 sh0[512] __attribute__((aligned(16)));
  __shared__ _Float16 sh1[512] __attribute__((aligned(16)));
  __shared__ float red[8][4];
  sh0[tid] = (_Float16)0.f; sh1[tid] = (_Float16)0.f;
  const float g = lng[tid], be = lnb[tid];
  const uint4* Arow = Apk + (size_t)tid * 64;  // 64 x (4 half2) = column o of A, k-packed
  __syncthreads();

  for (int t = 0; t < 2048; ++t) {
    float a0 = 0.f, a1 = 0.f;
    const uint4* s0p = (const uint4*)sh0;
    const uint4* s1p = (const uint4*)sh1;
#pragma unroll 8
    for (int i = 0; i < 64; ++i) {
      uint4 av = Arow[i];
      uint4 sv0 = s0p[i];
      uint4 sv1 = s1p[i];
      f16x2 aa[4], s0v[4], s1v[4];
      *(uint4*)aa = av; *(uint4*)s0v = sv0; *(uint4*)s1v = sv1;
#pragma unroll
      for (int j = 0; j < 4; ++j) {
        a0 = fdot2a(aa[j], s0v[j], a0);
        a1 = fdot2a(aa[j], s1v[j], a1);
      }
    }
    const float u0 = __bfloat162float(U[(b0 * 2048 + t) * 512 + tid]);
    const float u1 = __bfloat162float(U[(b1 * 2048 + t) * 512 + tid]);
    const float w0 = a0 + u0, w1 = a1 + u1;
    float s0 = w0, q0 = w0 * w0, s1 = w1, q1 = w1 * w1;
#pragma unroll
    for (int off = 32; off; off >>= 1) {
      s0 += __shfl_down(s0, off); q0 += __shfl_down(q0, off);
      s1 += __shfl_down(s1, off); q1 += __shfl_down(q1, off);
    }
    if (lane == 0) { red[wv][0] = s0; red[wv][1] = q0; red[wv][2] = s1; red[wv][3] = q1; }
    __syncthreads();   // partials visible; all waves done reading sh
    float fs0 = 0.f, fq0 = 0.f, fs1 = 0.f, fq1 = 0.f;
#pragma unroll
    for (int w2 = 0; w2 < 8; ++w2) {
      fs0 += red[w2][0]; fq0 += red[w2][1]; fs1 += red[w2][2]; fq1 += red[w2][3];
    }
    const float mu0 = fs0 * (1.f / 512.f), mu1 = fs1 * (1.f / 512.f);
    const float rs0 = rsqrtf(fq0 * (1.f / 512.f) - mu0 * mu0 + 1e-5f);
    const float rs1 = rsqrtf(fq1 * (1.f / 512.f) - mu1 * mu1 + 1e-5f);
    const float sn0 = (w0 - mu0) * rs0 * g + be;
    const float sn1 = (w1 - mu1) * rs1 * g + be;
    sh0[tid] = (_Float16)sn0; sh1[tid] = (_Float16)sn1;
    S[(b0 * 2048 + t) * 512 + tid] = __float2bfloat16(sn0);
    S[(b1 * 2048 + t) * 512 + tid] = __float2bfloat16(sn1);
    __syncthreads();   // sh update visible before next step's dots
  }
}

// ---------------- host launch ----------------
extern "C" void kernel_launch(void* const* d_in, const int* in_sizes, int n_in,
                              void* d_out, int out_size, void* d_ws, size_t ws_size,
                              hipStream_t stream) {
  (void)in_sizes; (void)n_in; (void)out_size; (void)ws_size;
  const float* x     = (const float*)d_in[0];
  const float* W_in  = (const float*)d_in[1];
  const float* b_in  = (const float*)d_in[2];
  const float* convw = (const float*)d_in[3];
  // d_in[4] conv_b: cancels in training-mode BN
  const float* bng   = (const float*)d_in[5];
  const float* bnb   = (const float*)d_in[6];
  const float* lng   = (const float*)d_in[7];
  const float* lnb   = (const float*)d_in[8];
  const float* Am    = (const float*)d_in[9];
  const float* Bm    = (const float*)d_in[10];
  const float* Cm    = (const float*)d_in[11];
  // d_in[12] output_length == T == 2048 (fixed)

  char* ws = (char*)d_ws;
  bf16*  xb    = (bf16*)(ws + 0ull);            // 67,108,864 B
  bf16*  vpad  = (bf16*)(ws + 67108864ull);     // 134,348,800 B (64 x 2050 x 512); later aliased as U
  bf16*  craw  = (bf16*)(ws + 201457664ull);    // 134,217,728 B
  bf16*  Sb    = (bf16*)(ws + 335675392ull);    // 134,217,728 B
  bf16*  Wt    = (bf16*)(ws + 469893120ull);    // 262,144 B
  bf16*  Wct   = (bf16*)(ws + 470155264ull);    // 1,572,864 B
  void*  Apk   = (void*)(ws + 471728128ull);    // 524,288 B (f16 packed A, o-major)
  bf16*  Ct    = (bf16*)(ws + 472252416ull);    // 262,144 B
  bf16*  Bmt   = (bf16*)(ws + 472514560ull);    // 524,288 B
  float* biasu = (float*)(ws + 473038848ull);   // 2,048 B
  float* sums  = (float*)(ws + 473040896ull);   // 4,096 B
  float* scsh  = (float*)(ws + 473044992ull);   // 4,096 B  -- total ~451 MiB

  kprep<<<4868, 256, 0, stream>>>(W_in, convw, Am, Cm, sums, vpad, Wt, Wct, (f16x2*)Apk, Ct);
  kx<<<32768, 256, 0, stream>>>((const float4*)x, (ushort4*)xb);
  // G1: v = silu(x @ W_in^T + b)  -> vpad (interior rows)
  kgemm<0><<<dim3(1024, 4), 256, 0, stream>>>(xb, 256, 0, Wt, 256, b_in, vpad);
  // G2: conv as GEMM over contiguous 1536-wide windows of vpad (lda=512, row skew for padding)
  kgemm<1><<<dim3(1024, 4), 256, 0, stream>>>(vpad, 512, 1024, Wct, 1536, nullptr, craw);
  bn_stats<<<1024, 512, 0, stream>>>(craw, sums);
  bn_finalize<<<1, 512, 0, stream>>>(sums, bng, bnb, scsh);
  build_bm<<<1026, 256, 0, stream>>>(Bm, scsh, Bmt, biasu);
  // G3: U = conv_raw @ (diag(sc)Bm) + sh@Bm  -> overwrite vpad region (dead) as U
  kgemm<2><<<dim3(1024, 4), 256, 0, stream>>>(craw, 512, 0, Bmt, 512, biasu, vpad);
  // sequential scan, 32 WGs x 2 batches
  krec<<<32, 512, 0, stream>>>((const uint4*)Apk, vpad, lng, lnb, Sb);
  // G4: Y = S @ C -> d_out fp32
  kgemm<3><<<dim3(1024, 2), 256, 0, stream>>>(Sb, 512, 0, Ct, 512, nullptr, d_out);
}

// Round 2
// 8672.985 us; speedup vs baseline: 3.7383x; 3.7383x over previous
//
#include <hip/hip_runtime.h>
#include <hip/hip_bf16.h>
#include <hip/hip_fp16.h>
#include <stdint.h>

// MambaBlock: B=64 T=2048 IN=256 STATE=512 OUT=256 K=3
// prep -> x->bf16 -> G1(silu proj) -> G2(conv-as-GEMM) -> BN stats
//      -> fold BN into Bm -> G3(U = conv_raw@Bm'+bias) -> transpose U
//      -> MFMA scan (A register/LDS-resident) -> G4(Y=S@C, f16)

using bf16 = __hip_bfloat16;
typedef short    bf16x8 __attribute__((ext_vector_type(8)));
typedef float    f32x4v __attribute__((ext_vector_type(4)));
typedef _Float16 f16x8  __attribute__((ext_vector_type(8)));

static __device__ inline unsigned short f2bf_bits(float f) {
  union { bf16 h; unsigned short u; } cv; cv.h = __float2bfloat16(f); return cv.u;
}
static __device__ inline float bflo(unsigned v) { return __builtin_bit_cast(float, v << 16); }
static __device__ inline float bfhi(unsigned v) { return __builtin_bit_cast(float, v & 0xFFFF0000u); }

// async global->LDS, 16B/lane; LDS dest = wave-uniform base + lane*16
static __device__ inline void glds16(const void* g, void* l) {
  __builtin_amdgcn_global_load_lds(
      (const __attribute__((address_space(1))) unsigned int*)g,
      (__attribute__((address_space(3))) unsigned int*)l, 16, 0, 0);
}

// DPP butterfly sum over each 16-lane row (off the LDS pipe)
template <int CTRL>
static __device__ inline float dppsum(float v) {
  int o = __builtin_amdgcn_update_dpp(0, __builtin_bit_cast(int, v), CTRL, 0xf, 0xf, true);
  return v + __builtin_bit_cast(float, o);
}
static __device__ inline float row16_sum(float v) {
  v = dppsum<0xB1>(v);   // quad_perm [1,0,3,2]  (xor 1)
  v = dppsum<0x4E>(v);   // quad_perm [2,3,0,1]  (xor 2)
  v = dppsum<0x141>(v);  // row_half_mirror      (pairs quads 0<->1, 2<->3)
  v = dppsum<0x140>(v);  // row_mirror           (pairs halves)
  return v;
}

// ---------------- prep: zero sums + vpad edges, build weights ----------------
__global__ void kprep(const float* __restrict__ W_in, const float* __restrict__ conv_w,
                      const float* __restrict__ A, const float* __restrict__ C,
                      float* __restrict__ sums, bf16* __restrict__ vpad,
                      bf16* __restrict__ Wt, bf16* __restrict__ Wct,
                      _Float16* __restrict__ Ctf, _Float16* __restrict__ Afr) {
  long idx = (long)blockIdx.x * 256 + threadIdx.x;
  if (idx < 1024) { sums[idx] = 0.f; return; }
  idx -= 1024;
  if (idx < 65536) {  // zero pad rows (t=-1, t=T) of vpad (64 x 2050 x 512)
    long b = idx >> 10, rem = idx & 1023, r = rem >> 9, col = rem & 511;
    long row = b * 2050 + (r ? 2049 : 0);
    vpad[row * 512 + col] = __float2bfloat16(0.f);
    return;
  }
  idx -= 65536;
  if (idx < 131072) { Wt[idx] = __float2bfloat16(W_in[idx]); return; } // (N=512,K=256)
  idx -= 131072;
  if (idx < 786432) { // Wct[o][kk*512+i] = conv_w[o,i,kk]   (N=512, K=1536)
    long o = idx / 1536, k = idx - o * 1536, kk = k >> 9, i = k & 511;
    Wct[idx] = __float2bfloat16(conv_w[(o * 512 + i) * 3 + kk]);
    return;
  }
  idx -= 786432;
  if (idx < 131072) { // Ctf[n][i] = C[i][n]  f16  (N=256, K=512)
    long n = idx >> 9, i = idx & 511;
    Ctf[idx] = (_Float16)C[i * 256 + n];
    return;
  }
  idx -= 131072;
  if (idx < 262144) { // A -> MFMA B-fragment order (f16)
    long k = idx >> 9, n = idx & 511;
    long w = n >> 7, nt = (n >> 4) & 7, cc = n & 15;
    long kt = k >> 5, qq = (k & 31) >> 3, j = k & 7;
    Afr[(((w * 8 + nt) * 16 + kt) * 64 + (qq * 16 + cc)) * 8 + j] = (_Float16)A[k * 512 + n];
  }
}

// ---------------- x fp32 -> bf16 ----------------
__global__ void kx(const float4* __restrict__ x, ushort4* __restrict__ xb) {
  size_t i = (size_t)blockIdx.x * 256 + threadIdx.x;
  float4 v = x[i];
  ushort4 o;
  o.x = f2bf_bits(v.x); o.y = f2bf_bits(v.y); o.z = f2bf_bits(v.z); o.w = f2bf_bits(v.w);
  xb[i] = o;
}

// ---------------- 128x128 MFMA GEMM, BK=64, 4 waves ----------------
// EPI 0: +bias, silu -> vpad scatter   EPI 1: bf16 (stride 512)
// EPI 2: +bias, bf16 (stride 512)      EPI 3: fp32 (stride 256)
template <int EPI, bool F16>
__global__ __launch_bounds__(256)
void kgemm(const bf16* __restrict__ Ag, long lda, long rowExtra,
           const bf16* __restrict__ Bg, int K,
           const float* __restrict__ bias, void* __restrict__ outp) {
  const int tid = threadIdx.x;
  const int lane = tid & 63;
  const int wv = tid >> 6;
  const int wm = wv >> 1, wn = wv & 1;
  const long m0 = (long)blockIdx.x * 128;
  const long n0 = (long)blockIdx.y * 128;
  __shared__ short At[128 * 64];
  __shared__ short Bt[128 * 64];
  f32x4v acc[4][4];
#pragma unroll
  for (int a = 0; a < 4; ++a)
#pragma unroll
    for (int b = 0; b < 4; ++b)
#pragma unroll
      for (int r = 0; r < 4; ++r) acc[a][b][r] = 0.f;

  const int rsub = lane >> 3;
  const int ksub = (lane & 7) * 8;

  for (int k0 = 0; k0 < K; k0 += 64) {
#pragma unroll
    for (int j = 0; j < 4; ++j) {
      const int c = wv * 4 + j;
      {
        long row = m0 + c * 8 + rsub;
        const bf16* gp = Ag + row * lda + (row >> 11) * rowExtra + k0 + ksub;
        glds16(gp, At + c * 512);
      }
      {
        long row = n0 + c * 8 + rsub;
        const bf16* gp = Bg + row * (long)K + k0 + ksub;
        glds16(gp, Bt + c * 512);
      }
    }
    __syncthreads();
#pragma unroll
    for (int h = 0; h < 2; ++h) {
      bf16x8 af[4], bf_[4];
      const int kb = h * 32 + (lane >> 4) * 8;
#pragma unroll
      for (int f = 0; f < 4; ++f) {
        af[f]  = *(const bf16x8*)(At + (wm * 64 + f * 16 + (lane & 15)) * 64 + kb);
        bf_[f] = *(const bf16x8*)(Bt + (wn * 64 + f * 16 + (lane & 15)) * 64 + kb);
      }
#pragma unroll
      for (int fm = 0; fm < 4; ++fm)
#pragma unroll
        for (int fn = 0; fn < 4; ++fn) {
          if constexpr (F16)
            acc[fm][fn] = __builtin_amdgcn_mfma_f32_16x16x32_f16(
                __builtin_bit_cast(f16x8, af[fm]), __builtin_bit_cast(f16x8, bf_[fn]),
                acc[fm][fn], 0, 0, 0);
          else
            acc[fm][fn] = __builtin_amdgcn_mfma_f32_16x16x32_bf16(af[fm], bf_[fn], acc[fm][fn], 0, 0, 0);
        }
    }
    __syncthreads();
  }

  const int q = lane >> 4, cL = lane & 15;
#pragma unroll
  for (int fm = 0; fm < 4; ++fm)
#pragma unroll
    for (int fn = 0; fn < 4; ++fn)
#pragma unroll
      for (int r = 0; r < 4; ++r) {
        const long m = m0 + wm * 64 + fm * 16 + q * 4 + r;
        const long n = n0 + wn * 64 + fn * 16 + cL;
        float v = acc[fm][fn][r];
        if constexpr (EPI == 0) {
          v += bias[n];
          const float s = v / (1.f + __expf(-v));
          const long row = (m >> 11) * 2050 + (m & 2047) + 1;
          ((bf16*)outp)[row * 512 + n] = __float2bfloat16(s);
        } else if constexpr (EPI == 1) {
          ((bf16*)outp)[m * 512 + n] = __float2bfloat16(v);
        } else if constexpr (EPI == 2) {
          ((bf16*)outp)[m * 512 + n] = __float2bfloat16(v + bias[n]);
        } else {
          ((float*)outp)[m * 256 + n] = v;
        }
      }
}

// ---------------- BN stats ----------------
__global__ __launch_bounds__(512)
void bn_stats(const bf16* __restrict__ cr, float* __restrict__ sums) {
  const int tid = threadIdx.x;
  const long base = (long)blockIdx.x * 128 * 512;
  float s = 0.f, q = 0.f;
  for (int r = 0; r < 128; ++r) {
    float v = __bfloat162float(cr[base + (long)r * 512 + tid]);
    s += v; q += v * v;
  }
  atomicAdd(&sums[tid], s);
  atomicAdd(&sums[512 + tid], q);
}

__global__ void bn_finalize(const float* __restrict__ sums, const float* __restrict__ gamma,
                            const float* __restrict__ beta, float* __restrict__ scsh) {
  const int n = threadIdx.x;
  const float mu = sums[n] * (1.f / 131072.f);
  const float var = sums[512 + n] * (1.f / 131072.f) - mu * mu;
  const float sc = gamma[n] * rsqrtf(var + 1e-5f);
  scsh[n] = sc;
  scsh[512 + n] = beta[n] - mu * sc;   // conv bias cancels in training-mode BN
}

__global__ void build_bm(const float* __restrict__ Bm, const float* __restrict__ scsh,
                         bf16* __restrict__ Bmt, float* __restrict__ biasu) {
  long idx = (long)blockIdx.x * 256 + threadIdx.x;
  if (idx < 262144) {
    long n = idx >> 9, i = idx & 511;
    Bmt[idx] = __float2bfloat16(Bm[i * 512 + n] * scsh[i]);
  } else if (idx < 262656) {
    int n = (int)(idx - 262144);
    float acc = 0.f;
    for (int i = 0; i < 512; ++i) acc += scsh[512 + i] * Bm[(long)i * 512 + n];
    biasu[n] = acc;
  }
}

// ---------------- U transpose: [b][t][n] -> [t*512+n][b] ----------------
__global__ __launch_bounds__(256)
void ktru(const ushort* __restrict__ U, ushort* __restrict__ Ut) {
  __shared__ ushort tile[64][65];
  const int tid = threadIdx.x;
  const int x = tid & 63, r = tid >> 6;
  const size_t tn0 = (size_t)blockIdx.x * 64;
#pragma unroll
  for (int i = 0; i < 16; ++i) {
    int b = i * 4 + r;
    tile[x][b] = U[(size_t)b * 1048576 + tn0 + x];
  }
  __syncthreads();
#pragma unroll
  for (int i = 0; i < 16; ++i) {
    int j = i * 4 + r;
    Ut[(tn0 + j) * 64 + x] = tile[j][x];
  }
}

// ---------------- MFMA scan: s = LN(s@A + u_t), 4 WGs x 16 batches ----------------
__global__ __launch_bounds__(256, 1)
void krec2(const _Float16* __restrict__ Afrag,  // frag-ordered A, 262144 f16
           const ushort* __restrict__ Ut,       // bf16 bits, [t*512+n][b]
           const float* __restrict__ lng, const float* __restrict__ lnb,
           _Float16* __restrict__ S) {          // f16 [b*2048+t][512]
  const int tid = threadIdx.x;
  const int lane = tid & 63, w = tid >> 6;
  const int q = lane >> 4, c = lane & 15;
  const int g = blockIdx.x;

  __shared__ _Float16 Alds[4 * 8 * 4 * 512] __attribute__((aligned(16)));  // 128 KB: kt 12..15
  __shared__ _Float16 slds[16 * 520] __attribute__((aligned(16)));         // 16.25 KB
  __shared__ float red[16 * 4 * 2] __attribute__((aligned(16)));           // [row][w][2]

  // A k-tiles 0..11 resident in VGPRs (384 regs)
  f16x8 Ar[96];
#pragma unroll
  for (int nt = 0; nt < 8; ++nt)
#pragma unroll
    for (int kt = 0; kt < 12; ++kt)
      Ar[nt * 12 + kt] = *(const f16x8*)(Afrag + (((w * 8 + nt) * 16 + kt) * 64 + lane) * 8);

  // k-tiles 12..15 -> LDS via async copy (frag layout preserved: lane*16B)
#pragma unroll
  for (int nt = 0; nt < 8; ++nt)
#pragma unroll
    for (int k2 = 0; k2 < 4; ++k2)
      glds16(Afrag + (((w * 8 + nt) * 16 + 12 + k2) * 64 + lane) * 8,
             &Alds[((w * 8 + nt) * 4 + k2) * 512]);

  for (int i = tid; i < 16 * 520; i += 256) slds[i] = (_Float16)0;

  float gg[8], bb[8];
#pragma unroll
  for (int nt = 0; nt < 8; ++nt) {
    int n = w * 128 + nt * 16 + c;
    gg[nt] = lng[n]; bb[nt] = lnb[n];
  }

  // U prefetch for t=0
  uint2 upre[8];
#pragma unroll
  for (int nt = 0; nt < 8; ++nt) {
    size_t n = (size_t)(w * 128 + nt * 16 + c);
    upre[nt] = *(const uint2*)(Ut + (n * 64 + g * 16 + q * 4));
  }
  __syncthreads();  // glds16 drained (vmcnt0) + slds zero visible

#pragma unroll 1
  for (int t = 0; t < 2048; ++t) {
    // store S(t-1) from slds (coalesced dwordx4); skipped at t=0 (slds=0)
    if (t > 0) {
#pragma unroll
      for (int r = 0; r < 4; ++r) {
        f16x8 v = *(const f16x8*)&slds[(w * 4 + r) * 520 + lane * 8];
        *(f16x8*)(S + ((size_t)(g * 16 + w * 4 + r) * 2048 + (t - 1)) * 512 + lane * 8) = v;
      }
    }
    // acc init = U_t (bf16 -> f32)
    f32x4v acc[8];
#pragma unroll
    for (int nt = 0; nt < 8; ++nt) {
      uint2 u = upre[nt];
      acc[nt][0] = bflo(u.x); acc[nt][1] = bfhi(u.x);
      acc[nt][2] = bflo(u.y); acc[nt][3] = bfhi(u.y);
    }
    // prefetch U_{t+1}
    const int tnx = (t < 2047) ? t + 1 : 2047;
#pragma unroll
    for (int nt = 0; nt < 8; ++nt) {
      size_t n = (size_t)(w * 128 + nt * 16 + c);
      upre[nt] = *(const uint2*)(Ut + (((size_t)tnx * 512 + n) * 64 + g * 16 + q * 4));
    }
    // MFMA phase: w_row += s_prev @ A  (reg tiles then LDS tiles)
#pragma unroll
    for (int kt = 0; kt < 12; ++kt) {
      f16x8 sf = *(const f16x8*)&slds[c * 520 + kt * 32 + q * 8];
#pragma unroll
      for (int nt = 0; nt < 8; ++nt)
        acc[nt] = __builtin_amdgcn_mfma_f32_16x16x32_f16(sf, Ar[nt * 12 + kt], acc[nt], 0, 0, 0);
    }
#pragma unroll
    for (int k2 = 0; k2 < 4; ++k2) {
      f16x8 sf = *(const f16x8*)&slds[c * 520 + (12 + k2) * 32 + q * 8];
#pragma unroll
      for (int nt = 0; nt < 8; ++nt) {
        f16x8 bfr = *(const f16x8*)&Alds[((w * 8 + nt) * 4 + k2) * 512 + lane * 8];
        acc[nt] = __builtin_amdgcn_mfma_f32_16x16x32_f16(sf, bfr, acc[nt], 0, 0, 0);
      }
    }
    // LN stats: per-row sum / sumsq over this wave's 128 cols
    float Sv[4] = {0.f, 0.f, 0.f, 0.f}, Qv[4] = {0.f, 0.f, 0.f, 0.f};
#pragma unroll
    for (int nt = 0; nt < 8; ++nt)
#pragma unroll
      for (int r = 0; r < 4; ++r) {
        Sv[r] += acc[nt][r];
        Qv[r] = fmaf(acc[nt][r], acc[nt][r], Qv[r]);
      }
#pragma unroll
    for (int r = 0; r < 4; ++r) { Sv[r] = row16_sum(Sv[r]); Qv[r] = row16_sum(Qv[r]); }
    if (c == 0) {
#pragma unroll
      for (int r = 0; r < 4; ++r)
        *(float2*)&red[((q * 4 + r) * 4 + w) * 2] = make_float2(Sv[r], Qv[r]);
    }
    __syncthreads();  // barrier 1: red visible; all slds reads of step t done
    float mu[4], rs[4];
#pragma unroll
    for (int r = 0; r < 4; ++r) {
      const float4 p0 = *(const float4*)&red[((q * 4 + r) * 4 + 0) * 2];
      const float4 p1 = *(const float4*)&red[((q * 4 + r) * 4 + 2) * 2];
      const float s  = p0.x + p0.z + p1.x + p1.z;
      const float qq = p0.y + p0.w + p1.y + p1.w;
      mu[r] = s * (1.f / 512.f);
      rs[r] = rsqrtf(qq * (1.f / 512.f) - mu[r] * mu[r] + 1e-5f);
    }
    // normalize, write s(t) to slds (f16)
#pragma unroll
    for (int nt = 0; nt < 8; ++nt)
#pragma unroll
      for (int r = 0; r < 4; ++r) {
        float v = (acc[nt][r] - mu[r]) * rs[r] * gg[nt] + bb[nt];
        slds[(q * 4 + r) * 520 + (w * 128 + nt * 16 + c)] = (_Float16)v;
      }
    __syncthreads();  // barrier 2: s(t) visible for step t+1
  }
  // tail: store S(2047)
#pragma unroll
  for (int r = 0; r < 4; ++r) {
    f16x8 v = *(const f16x8*)&slds[(w * 4 + r) * 520 + lane * 8];
    *(f16x8*)(S + ((size_t)(g * 16 + w * 4 + r) * 2048 + 2047) * 512 + lane * 8) = v;
  }
}

// ---------------- host launch ----------------
extern "C" void kernel_launch(void* const* d_in, const int* in_sizes, int n_in,
                              void* d_out, int out_size, void* d_ws, size_t ws_size,
                              hipStream_t stream) {
  (void)in_sizes; (void)n_in; (void)out_size; (void)ws_size;
  const float* x     = (const float*)d_in[0];
  const float* W_in  = (const float*)d_in[1];
  const float* b_in  = (const float*)d_in[2];
  const float* convw = (const float*)d_in[3];
  // d_in[4] conv_b: cancels in training-mode BN
  const float* bng   = (const float*)d_in[5];
  const float* bnb   = (const float*)d_in[6];
  const float* lng   = (const float*)d_in[7];
  const float* lnb   = (const float*)d_in[8];
  const float* Am    = (const float*)d_in[9];
  const float* Bm    = (const float*)d_in[10];
  const float* Cm    = (const float*)d_in[11];

  char* ws = (char*)d_ws;
  bf16*      xb    = (bf16*)(ws + 0ull);             // 67,108,864 B
  bf16*      bufA  = (bf16*)(ws + 67108864ull);      // 134,348,800 B: vpad -> U-flat -> Sb(f16)
  bf16*      bufB  = (bf16*)(ws + 201457664ull);     // 134,217,728 B: craw -> Ut
  bf16*      Wt    = (bf16*)(ws + 335675392ull);     // 262,144
  bf16*      Wct   = (bf16*)(ws + 335937536ull);     // 1,572,864
  _Float16*  Afr   = (_Float16*)(ws + 337510400ull); // 524,288
  _Float16*  Ctf   = (_Float16*)(ws + 338034688ull); // 262,144
  bf16*      Bmt   = (bf16*)(ws + 338296832ull);     // 524,288
  float*     biasu = (float*)(ws + 338821120ull);    // 2,048
  float*     sums  = (float*)(ws + 338823168ull);    // 4,096
  float*     scsh  = (float*)(ws + 338827264ull);    // 4,096  (end ~323 MiB)

  kprep<<<5380, 256, 0, stream>>>(W_in, convw, Am, Cm, sums, bufA, Wt, Wct, Ctf, Afr);
  kx<<<32768, 256, 0, stream>>>((const float4*)x, (ushort4*)xb);
  // G1: v = silu(x @ W_in^T + b)  -> vpad interior
  kgemm<0, false><<<dim3(1024, 4), 256, 0, stream>>>(xb, 256, 0, Wt, 256, b_in, bufA);
  // G2: conv as GEMM over 1536-wide windows of vpad (row skew for padding)
  kgemm<1, false><<<dim3(1024, 4), 256, 0, stream>>>(bufA, 512, 1024, Wct, 1536, nullptr, bufB);
  bn_stats<<<1024, 512, 0, stream>>>(bufB, sums);
  bn_finalize<<<1, 512, 0, stream>>>(sums, bng, bnb, scsh);
  build_bm<<<1026, 256, 0, stream>>>(Bm, scsh, Bmt, biasu);
  // G3: U = craw @ (diag(sc)Bm) + bias_u  -> bufA (flat [b*2048+t][n], vpad dead)
  kgemm<2, false><<<dim3(1024, 4), 256, 0, stream>>>(bufB, 512, 0, Bmt, 512, biasu, bufA);
  // transpose U -> [t*512+n][b] into bufB (craw dead)
  ktru<<<16384, 256, 0, stream>>>((const ushort*)bufA, (ushort*)bufB);
  // MFMA scan -> Sb (f16) into bufA (U-flat dead)
  krec2<<<4, 256, 0, stream>>>(Afr, (const ushort*)bufB, lng, lnb, (_Float16*)bufA);
  // G4: Y = S @ C -> d_out fp32 (f16 MFMA)
  kgemm<3, true><<<dim3(1024, 2), 256, 0, stream>>>(bufA, 512, 0, (const bf16*)Ctf, 512, nullptr, d_out);
}

// Round 3
// 8233.865 us; speedup vs baseline: 3.9376x; 1.0533x over previous
//
#include <hip/hip_runtime.h>
#include <hip/hip_bf16.h>
#include <hip/hip_fp16.h>
#include <stdint.h>

// MambaBlock: B=64 T=2048 IN=256 STATE=512 OUT=256 K=3
// prep -> x->bf16 -> G1(silu proj) -> G2(conv-as-GEMM) -> BN stats
//      -> fold BN into Bm -> G3(U = conv_raw@Bm'+bias, [t][b][n] layout)
//      -> MFMA scan (operand-swapped, asm barriers, LN gamma/beta folded)
//      -> G4(Y = S@C', f16, +beta@C bias)

using bf16 = __hip_bfloat16;
typedef short    bf16x8 __attribute__((ext_vector_type(8)));
typedef float    f32x4v __attribute__((ext_vector_type(4)));
typedef _Float16 f16x8  __attribute__((ext_vector_type(8)));
typedef _Float16 f16x4  __attribute__((ext_vector_type(4)));

static __device__ inline unsigned short f2bf_bits(float f) {
  union { bf16 h; unsigned short u; } cv; cv.h = __float2bfloat16(f); return cv.u;
}
static __device__ inline float bflo(unsigned v) { return __builtin_bit_cast(float, v << 16); }
static __device__ inline float bfhi(unsigned v) { return __builtin_bit_cast(float, v & 0xFFFF0000u); }

// async global->LDS, 16B/lane; LDS dest = wave-uniform base + lane*16
static __device__ inline void glds16(const void* g, void* l) {
  __builtin_amdgcn_global_load_lds(
      (const __attribute__((address_space(1))) unsigned int*)g,
      (__attribute__((address_space(3))) unsigned int*)l, 16, 0, 0);
}

// barrier that drains ONLY lgkm (LDS) — leaves global loads/stores in flight.
// All cross-wave data flows through LDS, so this is sufficient for krec2.
#define ASM_BAR() asm volatile("s_waitcnt lgkmcnt(0)\n\ts_barrier" ::: "memory")

// ---------------- prep: zero sums + vpad edges, build weights ----------------
__global__ void kprep(const float* __restrict__ W_in, const float* __restrict__ conv_w,
                      const float* __restrict__ A, const float* __restrict__ C,
                      const float* __restrict__ lng, const float* __restrict__ lnb,
                      float* __restrict__ sums, bf16* __restrict__ vpad,
                      bf16* __restrict__ Wt, bf16* __restrict__ Wct,
                      _Float16* __restrict__ Ctf, _Float16* __restrict__ Afr,
                      float* __restrict__ cbeta, float* __restrict__ ybeta) {
  long idx = (long)blockIdx.x * 256 + threadIdx.x;
  if (idx < 1024) { sums[idx] = 0.f; return; }
  idx -= 1024;
  if (idx < 65536) {  // zero pad rows (t=-1, t=T) of vpad (64 x 2050 x 512)
    long b = idx >> 10, rem = idx & 1023, r = rem >> 9, col = rem & 511;
    long row = b * 2050 + (r ? 2049 : 0);
    vpad[row * 512 + col] = __float2bfloat16(0.f);
    return;
  }
  idx -= 65536;
  if (idx < 131072) { Wt[idx] = __float2bfloat16(W_in[idx]); return; } // (N=512,K=256)
  idx -= 131072;
  if (idx < 786432) { // Wct[o][kk*512+i] = conv_w[o,i,kk]   (N=512, K=1536)
    long o = idx / 1536, k = idx - o * 1536, kk = k >> 9, i = k & 511;
    Wct[idx] = __float2bfloat16(conv_w[(o * 512 + i) * 3 + kk]);
    return;
  }
  idx -= 786432;
  if (idx < 131072) { // Ctf[n][i] = C[i][n]*gamma[i]  f16  (N=256, K=512)
    long n = idx >> 9, i = idx & 511;
    Ctf[idx] = (_Float16)(C[i * 256 + n] * lng[i]);
    return;
  }
  idx -= 131072;
  if (idx < 262144) { // A' = diag(gamma)A -> MFMA fragment order (f16)
    long k = idx >> 9, n = idx & 511;
    long w = n >> 7, nt = (n >> 4) & 7, cc = n & 15;
    long kt = k >> 5, qq = (k & 31) >> 3, j = k & 7;
    Afr[(((w * 8 + nt) * 16 + kt) * 64 + (qq * 16 + cc)) * 8 + j] =
        (_Float16)(A[k * 512 + n] * lng[k]);
    return;
  }
  idx -= 262144;
  if (idx < 512) { // cbeta[n] = sum_k beta[k]*A[k][n]
    int n = (int)idx;
    float acc = 0.f;
    for (int k = 0; k < 512; ++k) acc += lnb[k] * A[(long)k * 512 + n];
    cbeta[n] = acc;
    return;
  }
  idx -= 512;
  if (idx < 256) { // ybeta[n] = sum_i beta[i]*C[i][n]
    int n = (int)idx;
    float acc = 0.f;
    for (int i = 0; i < 512; ++i) acc += lnb[i] * C[(long)i * 256 + n];
    ybeta[n] = acc;
  }
}

// ---------------- x fp32 -> bf16 ----------------
__global__ void kx(const float4* __restrict__ x, ushort4* __restrict__ xb) {
  size_t i = (size_t)blockIdx.x * 256 + threadIdx.x;
  float4 v = x[i];
  ushort4 o;
  o.x = f2bf_bits(v.x); o.y = f2bf_bits(v.y); o.z = f2bf_bits(v.z); o.w = f2bf_bits(v.w);
  xb[i] = o;
}

// ---------------- 128x128 MFMA GEMM, BK=64, 4 waves ----------------
// EPI 0: +bias, silu -> vpad scatter   EPI 1: bf16 (stride 512)
// EPI 2: +bias, bf16 -> U[t][b][n]     EPI 3: +bias, fp32 (stride 256)
template <int EPI, bool F16>
__global__ __launch_bounds__(256)
void kgemm(const bf16* __restrict__ Ag, long lda, long rowExtra,
           const bf16* __restrict__ Bg, int K,
           const float* __restrict__ bias, void* __restrict__ outp) {
  const int tid = threadIdx.x;
  const int lane = tid & 63;
  const int wv = tid >> 6;
  const int wm = wv >> 1, wn = wv & 1;
  const long m0 = (long)blockIdx.x * 128;
  const long n0 = (long)blockIdx.y * 128;
  __shared__ short At[128 * 64];
  __shared__ short Bt[128 * 64];
  f32x4v acc[4][4];
#pragma unroll
  for (int a = 0; a < 4; ++a)
#pragma unroll
    for (int b = 0; b < 4; ++b)
#pragma unroll
      for (int r = 0; r < 4; ++r) acc[a][b][r] = 0.f;

  const int rsub = lane >> 3;
  const int ksub = (lane & 7) * 8;

  for (int k0 = 0; k0 < K; k0 += 64) {
#pragma unroll
    for (int j = 0; j < 4; ++j) {
      const int c = wv * 4 + j;
      {
        long row = m0 + c * 8 + rsub;
        const bf16* gp = Ag + row * lda + (row >> 11) * rowExtra + k0 + ksub;
        glds16(gp, At + c * 512);
      }
      {
        long row = n0 + c * 8 + rsub;
        const bf16* gp = Bg + row * (long)K + k0 + ksub;
        glds16(gp, Bt + c * 512);
      }
    }
    __syncthreads();
#pragma unroll
    for (int h = 0; h < 2; ++h) {
      bf16x8 af[4], bf_[4];
      const int kb = h * 32 + (lane >> 4) * 8;
#pragma unroll
      for (int f = 0; f < 4; ++f) {
        af[f]  = *(const bf16x8*)(At + (wm * 64 + f * 16 + (lane & 15)) * 64 + kb);
        bf_[f] = *(const bf16x8*)(Bt + (wn * 64 + f * 16 + (lane & 15)) * 64 + kb);
      }
#pragma unroll
      for (int fm = 0; fm < 4; ++fm)
#pragma unroll
        for (int fn = 0; fn < 4; ++fn) {
          if constexpr (F16)
            acc[fm][fn] = __builtin_amdgcn_mfma_f32_16x16x32_f16(
                __builtin_bit_cast(f16x8, af[fm]), __builtin_bit_cast(f16x8, bf_[fn]),
                acc[fm][fn], 0, 0, 0);
          else
            acc[fm][fn] = __builtin_amdgcn_mfma_f32_16x16x32_bf16(af[fm], bf_[fn], acc[fm][fn], 0, 0, 0);
        }
    }
    __syncthreads();
  }

  const int q = lane >> 4, cL = lane & 15;
#pragma unroll
  for (int fm = 0; fm < 4; ++fm)
#pragma unroll
    for (int fn = 0; fn < 4; ++fn)
#pragma unroll
      for (int r = 0; r < 4; ++r) {
        const long m = m0 + wm * 64 + fm * 16 + q * 4 + r;
        const long n = n0 + wn * 64 + fn * 16 + cL;
        float v = acc[fm][fn][r];
        if constexpr (EPI == 0) {
          v += bias[n];
          const float s = v / (1.f + __expf(-v));
          const long row = (m >> 11) * 2050 + (m & 2047) + 1;
          ((bf16*)outp)[row * 512 + n] = __float2bfloat16(s);
        } else if constexpr (EPI == 1) {
          ((bf16*)outp)[m * 512 + n] = __float2bfloat16(v);
        } else if constexpr (EPI == 2) {
          // U layout [t][b][n]: m = b*2048+t  ->  row' = t*64 + b
          const long rowp = (m & 2047) * 64 + (m >> 11);
          ((bf16*)outp)[rowp * 512 + n] = __float2bfloat16(v + bias[n]);
        } else {
          ((float*)outp)[m * 256 + n] = v + bias[n];
        }
      }
}

// ---------------- BN stats ----------------
__global__ __launch_bounds__(512)
void bn_stats(const bf16* __restrict__ cr, float* __restrict__ sums) {
  const int tid = threadIdx.x;
  const long base = (long)blockIdx.x * 128 * 512;
  float s = 0.f, q = 0.f;
  for (int r = 0; r < 128; ++r) {
    float v = __bfloat162float(cr[base + (long)r * 512 + tid]);
    s += v; q += v * v;
  }
  atomicAdd(&sums[tid], s);
  atomicAdd(&sums[512 + tid], q);
}

__global__ void bn_finalize(const float* __restrict__ sums, const float* __restrict__ gamma,
                            const float* __restrict__ beta, float* __restrict__ scsh) {
  const int n = threadIdx.x;
  const float mu = sums[n] * (1.f / 131072.f);
  const float var = sums[512 + n] * (1.f / 131072.f) - mu * mu;
  const float sc = gamma[n] * rsqrtf(var + 1e-5f);
  scsh[n] = sc;
  scsh[512 + n] = beta[n] - mu * sc;   // conv bias cancels in training-mode BN
}

// Bmt[n][i] = Bm[i][n]*sc[i] ; biasu[n] = shift@Bm + beta@A'
__global__ void build_bm(const float* __restrict__ Bm, const float* __restrict__ scsh,
                         const float* __restrict__ cbeta,
                         bf16* __restrict__ Bmt, float* __restrict__ biasu) {
  long idx = (long)blockIdx.x * 256 + threadIdx.x;
  if (idx < 262144) {
    long n = idx >> 9, i = idx & 511;
    Bmt[idx] = __float2bfloat16(Bm[i * 512 + n] * scsh[i]);
  } else if (idx < 262656) {
    int n = (int)(idx - 262144);
    float acc = cbeta[n];
    for (int i = 0; i < 512; ++i) acc += scsh[512 + i] * Bm[(long)i * 512 + n];
    biasu[n] = acc;
  }
}

// ---------------- MFMA scan (operand-swapped): w^T = A'^T @ z^T + U ----------------
// 4 WGs x 16 batches; z = (w-mu)*rsig stored (gamma/beta folded into A', C', biases).
__global__ __launch_bounds__(256, 1)
void krec2(const _Float16* __restrict__ Afrag,  // frag-ordered diag(g)A, 262144 f16
           const ushort* __restrict__ U2,       // bf16 bits, [t][b][n]
           const float* __restrict__ cbeta,     // beta@A (t=0 correction)
           _Float16* __restrict__ S) {          // f16 z, [b*2048+t][512]
  const int tid = threadIdx.x;
  const int lane = tid & 63, w = tid >> 6;
  const int q = lane >> 4, c = lane & 15;
  const int g = blockIdx.x;

  __shared__ _Float16 Alds[4 * 8 * 4 * 512] __attribute__((aligned(16)));  // 128 KB: kt 12..15
  __shared__ _Float16 slds[16 * 520] __attribute__((aligned(16)));         // [batch][n+pad]
  __shared__ float red[128] __attribute__((aligned(16)));                  // [c][w]{S,Q}

  // A k-tiles 0..11 resident in VGPR/AGPR (384 regs)
  f16x8 Ar[96];
#pragma unroll
  for (int mt = 0; mt < 8; ++mt)
#pragma unroll
    for (int kt = 0; kt < 12; ++kt)
      Ar[mt * 12 + kt] = *(const f16x8*)(Afrag + (((w * 8 + mt) * 16 + kt) * 64 + lane) * 8);

  // k-tiles 12..15 -> LDS via async copy (frag layout: lane*16B)
#pragma unroll
  for (int mt = 0; mt < 8; ++mt)
#pragma unroll
    for (int k2 = 0; k2 < 4; ++k2)
      glds16(Afrag + (((w * 8 + mt) * 16 + 12 + k2) * 64 + lane) * 8,
             &Alds[((w * 8 + mt) * 4 + k2) * 512]);

  for (int i = tid; i < 16 * 520; i += 256) slds[i] = (_Float16)0;

  const int nb = w * 128 + q * 4;  // this lane's n-base (plus mt*16)
  // U prefetch for t=0
  uint2 upre[8];
#pragma unroll
  for (int mt = 0; mt < 8; ++mt)
    upre[mt] = *(const uint2*)(U2 + ((size_t)(g * 16 + c)) * 512 + nb + mt * 16);
  __syncthreads();  // drains glds16 (vmcnt) + slds zero visible

#pragma unroll 1
  for (int t = 0; t < 2048; ++t) {
    // store z(t-1) from slds (coalesced b128); skipped at t=0
    if (t > 0) {
#pragma unroll
      for (int r = 0; r < 4; ++r) {
        f16x8 v = *(const f16x8*)&slds[(w * 4 + r) * 520 + lane * 8];
        *(f16x8*)(S + ((size_t)(g * 16 + w * 4 + r) * 2048 + (t - 1)) * 512 + lane * 8) = v;
      }
    }
    // acc init = U_t (bf16 -> f32); rows r = consecutive n
    f32x4v acc[8];
#pragma unroll
    for (int mt = 0; mt < 8; ++mt) {
      uint2 u = upre[mt];
      acc[mt][0] = bflo(u.x); acc[mt][1] = bfhi(u.x);
      acc[mt][2] = bflo(u.y); acc[mt][3] = bfhi(u.y);
    }
    if (t == 0) {  // remove beta@A fold (s_{-1}=0, not an LN output)
#pragma unroll
      for (int mt = 0; mt < 8; ++mt) {
        float4 cb = *(const float4*)(cbeta + nb + mt * 16);
        acc[mt][0] -= cb.x; acc[mt][1] -= cb.y; acc[mt][2] -= cb.z; acc[mt][3] -= cb.w;
      }
    }
    // prefetch U_{t+1} (stays in flight across asm barriers)
    const int tnx = (t < 2047) ? t + 1 : 2047;
#pragma unroll
    for (int mt = 0; mt < 8; ++mt)
      upre[mt] = *(const uint2*)(U2 + ((size_t)tnx * 64 + g * 16 + c) * 512 + nb + mt * 16);
    // MFMA: A'-tiles (A-operand) x z-frags (B-operand, read from slds)
#pragma unroll
    for (int kt = 0; kt < 12; ++kt) {
      f16x8 sf = *(const f16x8*)&slds[c * 520 + kt * 32 + q * 8];
#pragma unroll
      for (int mt = 0; mt < 8; ++mt)
        acc[mt] = __builtin_amdgcn_mfma_f32_16x16x32_f16(Ar[mt * 12 + kt], sf, acc[mt], 0, 0, 0);
    }
#pragma unroll
    for (int k2 = 0; k2 < 4; ++k2) {
      f16x8 sf = *(const f16x8*)&slds[c * 520 + (12 + k2) * 32 + q * 8];
#pragma unroll
      for (int mt = 0; mt < 8; ++mt) {
        f16x8 af = *(const f16x8*)&Alds[((w * 8 + mt) * 4 + k2) * 512 + lane * 8];
        acc[mt] = __builtin_amdgcn_mfma_f32_16x16x32_f16(af, sf, acc[mt], 0, 0, 0);
      }
    }
    // LN stats for batch c: in-reg over (mt,r), cross-lane over q via shfl_xor
    float Sv = 0.f, Qv = 0.f;
#pragma unroll
    for (int mt = 0; mt < 8; ++mt)
#pragma unroll
      for (int r = 0; r < 4; ++r) {
        Sv += acc[mt][r];
        Qv = fmaf(acc[mt][r], acc[mt][r], Qv);
      }
    Sv += __shfl_xor(Sv, 16); Sv += __shfl_xor(Sv, 32);
    Qv += __shfl_xor(Qv, 16); Qv += __shfl_xor(Qv, 32);
    if (q == 0) *(float2*)&red[(c * 4 + w) * 2] = make_float2(Sv, Qv);
    ASM_BAR();  // barrier 1: red visible; slds reads of step t done
    const float4 p0 = *(const float4*)&red[c * 8];
    const float4 p1 = *(const float4*)&red[c * 8 + 4];
    const float fs = p0.x + p0.z + p1.x + p1.z;
    const float fq = p0.y + p0.w + p1.y + p1.w;
    const float mu = fs * (1.f / 512.f);
    const float rs = rsqrtf(fq * (1.f / 512.f) - mu * mu + 1e-5f);
    const float off = -mu * rs;
    // z = (w-mu)*rs -> slds as f16x4 (one b64 per mt)
#pragma unroll
    for (int mt = 0; mt < 8; ++mt) {
      f16x4 pk;
#pragma unroll
      for (int r = 0; r < 4; ++r) pk[r] = (_Float16)fmaf(acc[mt][r], rs, off);
      *(f16x4*)&slds[c * 520 + nb + mt * 16] = pk;
    }
    ASM_BAR();  // barrier 2: z(t) visible for step t+1
  }
  // tail: store z(2047)
#pragma unroll
  for (int r = 0; r < 4; ++r) {
    f16x8 v = *(const f16x8*)&slds[(w * 4 + r) * 520 + lane * 8];
    *(f16x8*)(S + ((size_t)(g * 16 + w * 4 + r) * 2048 + 2047) * 512 + lane * 8) = v;
  }
}

// ---------------- host launch ----------------
extern "C" void kernel_launch(void* const* d_in, const int* in_sizes, int n_in,
                              void* d_out, int out_size, void* d_ws, size_t ws_size,
                              hipStream_t stream) {
  (void)in_sizes; (void)n_in; (void)out_size; (void)ws_size;
  const float* x     = (const float*)d_in[0];
  const float* W_in  = (const float*)d_in[1];
  const float* b_in  = (const float*)d_in[2];
  const float* convw = (const float*)d_in[3];
  // d_in[4] conv_b: cancels in training-mode BN
  const float* bng   = (const float*)d_in[5];
  const float* bnb   = (const float*)d_in[6];
  const float* lng   = (const float*)d_in[7];
  const float* lnb   = (const float*)d_in[8];
  const float* Am    = (const float*)d_in[9];
  const float* Bm    = (const float*)d_in[10];
  const float* Cm    = (const float*)d_in[11];

  char* ws = (char*)d_ws;
  bf16*      xb    = (bf16*)(ws + 0ull);             // 67,108,864 B
  bf16*      bufA  = (bf16*)(ws + 67108864ull);      // 134,348,800 B: vpad -> U2[t][b][n]
  bf16*      bufB  = (bf16*)(ws + 201457664ull);     // 134,217,728 B: craw -> S (f16)
  bf16*      Wt    = (bf16*)(ws + 335675392ull);     // 262,144
  bf16*      Wct   = (bf16*)(ws + 335937536ull);     // 1,572,864
  _Float16*  Afr   = (_Float16*)(ws + 337510400ull); // 524,288
  _Float16*  Ctf   = (_Float16*)(ws + 338034688ull); // 262,144
  bf16*      Bmt   = (bf16*)(ws + 338296832ull);     // 524,288
  float*     biasu = (float*)(ws + 338821120ull);    // 2,048
  float*     sums  = (float*)(ws + 338823168ull);    // 4,096
  float*     scsh  = (float*)(ws + 338827264ull);    // 4,096
  float*     cbeta = (float*)(ws + 338831360ull);    // 2,048
  float*     ybeta = (float*)(ws + 338833408ull);    // 1,024   (end ~323 MiB)

  kprep<<<5383, 256, 0, stream>>>(W_in, convw, Am, Cm, lng, lnb, sums, bufA, Wt, Wct, Ctf, Afr,
                                  cbeta, ybeta);
  kx<<<32768, 256, 0, stream>>>((const float4*)x, (ushort4*)xb);
  // G1: v = silu(x @ W_in^T + b)  -> vpad interior
  kgemm<0, false><<<dim3(1024, 4), 256, 0, stream>>>(xb, 256, 0, Wt, 256, b_in, bufA);
  // G2: conv as GEMM over 1536-wide windows of vpad (row skew for padding)
  kgemm<1, false><<<dim3(1024, 4), 256, 0, stream>>>(bufA, 512, 1024, Wct, 1536, nullptr, bufB);
  bn_stats<<<1024, 512, 0, stream>>>(bufB, sums);
  bn_finalize<<<1, 512, 0, stream>>>(sums, bng, bnb, scsh);
  build_bm<<<1026, 256, 0, stream>>>(Bm, scsh, cbeta, Bmt, biasu);
  // G3: U = craw @ (diag(sc)Bm) + biasu  -> bufA as [t][b][n] (vpad dead)
  kgemm<2, false><<<dim3(1024, 4), 256, 0, stream>>>(bufB, 512, 0, Bmt, 512, biasu, bufA);
  // MFMA scan -> z into bufB (craw dead)
  krec2<<<4, 256, 0, stream>>>(Afr, (const ushort*)bufA, cbeta, (_Float16*)bufB);
  // G4: Y = z @ (diag(g)C) + beta@C -> d_out fp32
  kgemm<3, true><<<dim3(1024, 2), 256, 0, stream>>>(bufB, 512, 0, (const bf16*)Ctf, 512, ybeta, d_out);
}